// Round 12
// baseline (1817.370 us; speedup 1.0000x reference)
//
#include <hip/hip_runtime.h>
#include <math.h>

#define N_PTS 512
#define HID 128
#define KNN 8
#define MT 16              // m-tile per block (pairs)
#define NTHREADS 256

// Persistent scratch in static device globals.
__device__ float g_refv[N_PTS * KNN * 3];  // [n][k][xyz] neighbor ref vectors
__device__ float g_wdT[HID * HID];         // WdT[h][g] = Wd[g][h]
__device__ float g_waT[HID * HID];         // WaT[h][g] = Wa[g][h]

// -------- prep: kNN (golden-mimic f32; r8 telemetry proved == f64 true set) --
__global__ void __launch_bounds__(256) prep_kernel(
    const float* __restrict__ points, const float* __restrict__ Wd,
    const float* __restrict__ Wa)
{
    __shared__ float spts[N_PTS * 3];
    __shared__ float s_arr[N_PTS];
    const int t = threadIdx.x;
    const int tid = blockIdx.x * 256 + t;

    for (int i = t; i < N_PTS * 3; i += 256) spts[i] = points[i];
    __syncthreads();
    for (int i = t; i < N_PTS; i += 256) {
        const float x = spts[i * 3 + 0], y = spts[i * 3 + 1], z = spts[i * 3 + 2];
        s_arr[i] = __fadd_rn(__fadd_rn(__fmul_rn(x, x), __fmul_rn(y, y)),
                             __fmul_rn(z, z));
    }
    __syncthreads();

    for (int idx = tid; idx < HID * HID; idx += 512) {
        const int r = idx >> 7, c = idx & 127;
        g_wdT[c * HID + r] = Wd[idx];
        g_waT[c * HID + r] = Wa[idx];
    }

    const int n = tid;
    if (n < N_PTS) {
        const float px = spts[n * 3 + 0], py = spts[n * 3 + 1], pz = spts[n * 3 + 2];
        const float sn = s_arr[n];
        float bdist[9]; int bidx[9];
#pragma unroll
        for (int j = 0; j < 9; ++j) { bdist[j] = 1e30f; bidx[j] = -1; }
        for (int m = 0; m < N_PTS; ++m) {
            const float qx = spts[m * 3 + 0], qy = spts[m * 3 + 1], qz = spts[m * 3 + 2];
            float dot = __fmul_rn(px, qx);
            dot = fmaf(py, qy, dot);
            dot = fmaf(pz, qz, dot);
            float sq = __fsub_rn(__fadd_rn(sn, s_arr[m]), __fadd_rn(dot, dot));
            sq = fmaxf(sq, 0.0f);
            const float dm = __fsqrt_rn(sq);
            if (dm < bdist[8]) {                     // strict <: ties keep earlier index
                float cd = dm; int ci = m;
#pragma unroll
                for (int j = 0; j < 9; ++j) {
                    const bool less = cd < bdist[j];
                    const float td = less ? bdist[j] : cd;
                    const int   ti = less ? bidx[j]  : ci;
                    bdist[j] = less ? cd : bdist[j];
                    bidx[j]  = less ? ci : bidx[j];
                    cd = td; ci = ti;
                }
            }
        }
#pragma unroll
        for (int k = 0; k < KNN; ++k) {
            const int j = bidx[k + 1];
            g_refv[(n * KNN + k) * 3 + 0] = __fsub_rn(spts[j * 3 + 0], px);
            g_refv[(n * KNN + k) * 3 + 1] = __fsub_rn(spts[j * 3 + 1], py);
            g_refv[(n * KNN + k) * 3 + 2] = __fsub_rn(spts[j * 3 + 2], pz);
        }
    }
}

// -------- main: tiled; degenerate angle (sin_v==0) -> 0, NEVER pi ----------
// XLA/BLAS dot reductions init with +0, so ref's diagonal cos_v is +0 and its
// angle is 0.  Per-element product sums yield -0 (all-neg ref) -> atan2 = pi,
// which was the 12-round frozen 0.96875 error.  Force 0 when sin_v == 0.
__global__ void __launch_bounds__(NTHREADS, 2) main_kernel(
    const float* __restrict__ points, const float* __restrict__ bd,
    const float* __restrict__ ba, float* __restrict__ out)
{
    __shared__ __align__(16) float sEa[HID][KNN][MT];  // 64 KB  [h][k][pair]
    __shared__ __align__(16) float sEd[HID][MT];       // 8 KB   [h][pair]
    __shared__ float sAidx[MT][KNN];
    __shared__ float sDidx[MT];
    __shared__ float sDiv[64];
    __shared__ float sRef[KNN][3];
    __shared__ float sPm[MT][3];
    __shared__ float sPn[3];

    const int t = threadIdx.x;
    const int n = blockIdx.y;
    const int m0 = blockIdx.x * MT;

    // ---- stage small data ----
    if (t < 64) sDiv[t] = expf(-0.14391156831212787f * (float)t); // 10000^(-t/64)
    if (t < 3) sPn[t] = points[n * 3 + t];
    if (t >= 64 && t < 64 + MT * 3) { int i = t - 64;  sPm[i / 3][i % 3] = points[m0 * 3 + i]; }
    if (t >= 128 && t < 128 + KNN * 3) { int i = t - 128; sRef[i / 3][i % 3] = g_refv[n * KNN * 3 + i]; }
    __syncthreads();

    // ---- geometry ----
    if (t < MT) {
        const float qx = sPm[t][0], qy = sPm[t][1], qz = sPm[t][2];
        const float sn = __fadd_rn(__fadd_rn(__fmul_rn(sPn[0], sPn[0]), __fmul_rn(sPn[1], sPn[1])), __fmul_rn(sPn[2], sPn[2]));
        const float sm = __fadd_rn(__fadd_rn(__fmul_rn(qx, qx), __fmul_rn(qy, qy)), __fmul_rn(qz, qz));
        float dot = __fmul_rn(sPn[0], qx);
        dot = fmaf(sPn[1], qy, dot);
        dot = fmaf(sPn[2], qz, dot);
        float sq = __fsub_rn(__fadd_rn(sn, sm), __fadd_rn(dot, dot));
        sq = fmaxf(sq, 0.0f);
        sDidx[t] = __fdiv_rn(__fsqrt_rn(sq), 0.2f);   // dist / SIGMA_D
    }
    if (t < MT * KNN) {
        const int pair = t >> 3, k = t & 7;
        const float ax = sPm[pair][0] - sPn[0];
        const float ay = sPm[pair][1] - sPn[1];
        const float az = sPm[pair][2] - sPn[2];
        const float rx = sRef[k][0], ry = sRef[k][1], rz = sRef[k][2];
        const float cx = ry * az - rz * ay;
        const float cy = rz * ax - rx * az;
        const float cz = rx * ay - ry * ax;
        const float sv = sqrtf(cx * cx + cy * cy + cz * cz);
        const float cv = rx * ax + ry * ay + rz * az;
        float ang;
        if (sv == 0.0f) ang = 0.0f;          // degenerate: match +0-init dot (never pi)
        else            ang = atan2f(sv, cv);
        sAidx[pair][k] = ang * 3.8197186342054885f;   // * 180/(15*pi)
    }
    __syncthreads();

    // ---- embeddings into LDS ----
    for (int idx = t; idx < MT * 64; idx += NTHREADS) {
        const int pair = idx >> 6, i = idx & 63;
        const float om = sDidx[pair] * sDiv[i];
        float s, c; sincosf(om, &s, &c);
        sEd[2 * i][pair] = s; sEd[2 * i + 1][pair] = c;
    }
    for (int idx = t; idx < MT * KNN * 64; idx += NTHREADS) {
        const int pair = idx >> 9, k = (idx >> 6) & 7, i = idx & 63;
        const float om = sAidx[pair][k] * sDiv[i];
        float s, c; sincosf(om, &s, &c);
        sEa[2 * i][k][pair] = s; sEa[2 * i + 1][k][pair] = c;
    }
    __syncthreads();

    // ---- matvecs: thread owns (g, 8 pairs); h outer so WT rows read once ----
    const int g = t & 127;
    const int pg0 = (t >> 7) * 8;

    float accd[8];
    float acca[8][8];
#pragma unroll
    for (int p = 0; p < 8; ++p) accd[p] = 0.0f;
#pragma unroll
    for (int kk = 0; kk < 8; ++kk)
#pragma unroll
        for (int p = 0; p < 8; ++p) acca[kk][p] = 0.0f;

#define FMA4(ACC, B, V, W) \
    ACC[(B) + 0] += (V).x * (W); ACC[(B) + 1] += (V).y * (W); \
    ACC[(B) + 2] += (V).z * (W); ACC[(B) + 3] += (V).w * (W);

    for (int h = 0; h < HID; ++h) {
        const float wd = g_wdT[h * HID + g];
        const float wa = g_waT[h * HID + g];
        const float4 e0 = *(const float4*)&sEd[h][pg0];
        const float4 e1 = *(const float4*)&sEd[h][pg0 + 4];
        FMA4(accd, 0, e0, wd);
        FMA4(accd, 4, e1, wd);
#pragma unroll
        for (int kk = 0; kk < 8; ++kk) {
            const float4 a0 = *(const float4*)&sEa[h][kk][pg0];
            const float4 a1 = *(const float4*)&sEa[h][kk][pg0 + 4];
            FMA4(acca[kk], 0, a0, wa);
            FMA4(acca[kk], 4, a1, wa);
        }
    }
#undef FMA4

    const float bdv = bd[g];
    const float bav = ba[g];
#pragma unroll
    for (int p = 0; p < 8; ++p) {
        float mx = acca[0][p];
#pragma unroll
        for (int kk = 1; kk < 8; ++kk) mx = fmaxf(mx, acca[kk][p]);
        const int m = m0 + pg0 + p;
        out[(n * N_PTS + m) * HID + g] = accd[p] + bdv + mx + bav;
    }
}

extern "C" void kernel_launch(void* const* d_in, const int* in_sizes, int n_in,
                              void* d_out, int out_size, void* d_ws, size_t ws_size,
                              hipStream_t stream) {
    (void)in_sizes; (void)n_in; (void)out_size; (void)d_ws; (void)ws_size;
    const float* points = (const float*)d_in[0];
    const float* Wd     = (const float*)d_in[1];
    const float* bd     = (const float*)d_in[2];
    const float* Wa     = (const float*)d_in[3];
    const float* ba     = (const float*)d_in[4];
    float* out = (float*)d_out;

    prep_kernel<<<2, 256, 0, stream>>>(points, Wd, Wa);

    dim3 grid(N_PTS / MT, N_PTS);
    main_kernel<<<grid, NTHREADS, 0, stream>>>(points, bd, ba, out);
}

// Round 13
// 321.996 us; speedup vs baseline: 5.6441x; 5.6441x over previous
//
#include <hip/hip_runtime.h>
#include <math.h>

#define N_PTS 512
#define HID 128
#define KNN 8
#define MT 16               // m-tile per block
#define NTHREADS 512
#define NROWS 144           // 16 d rows + 128 a rows (8k x 16m)

typedef __attribute__((ext_vector_type(8))) short short8_t;   // 8 bf16 (4 VGPRs)
typedef __attribute__((ext_vector_type(4))) float f32x4_t;    // MFMA acc

// Persistent scratch in static device globals.
__device__ float g_refv[N_PTS * KNN * 3];          // [n][k][xyz] neighbor ref vectors
__device__ unsigned short g_wfrag[2 * 8 * 4 * 64 * 8]; // [sel][gtile][ktile][lane][j] bf16 B-frags

__device__ __forceinline__ unsigned short f2bf(float f) {   // RNE f32->bf16
    const unsigned int u = __float_as_uint(f);
    return (unsigned short)((u + 0x7FFFu + ((u >> 16) & 1u)) >> 16);
}

// -------- prep: kNN (r12-validated verbatim) + W -> bf16 B-fragment layout ---
__global__ void __launch_bounds__(256) prep_kernel(
    const float* __restrict__ points, const float* __restrict__ Wd,
    const float* __restrict__ Wa)
{
    __shared__ float spts[N_PTS * 3];
    __shared__ float s_arr[N_PTS];
    const int t = threadIdx.x;
    const int tid = blockIdx.x * 256 + t;

    for (int i = t; i < N_PTS * 3; i += 256) spts[i] = points[i];
    __syncthreads();
    for (int i = t; i < N_PTS; i += 256) {
        const float x = spts[i * 3 + 0], y = spts[i * 3 + 1], z = spts[i * 3 + 2];
        s_arr[i] = __fadd_rn(__fadd_rn(__fmul_rn(x, x), __fmul_rn(y, y)),
                             __fmul_rn(z, z));
    }
    __syncthreads();

    // W[g][k] -> B-frag position (col=lane&15 is g, k = ktile*32 + (lane>>4)*8 + j)
    for (int idx = tid; idx < 2 * HID * HID; idx += 512) {
        const int sel = idx >> 14;          // 0 = Wd, 1 = Wa
        const int rem = idx & 16383;
        const int gg = rem >> 7, kk = rem & 127;
        const int gtile = gg >> 4, glo = gg & 15;
        const int ktile = kk >> 5, kmid = (kk >> 3) & 3, j = kk & 7;
        const int lane = kmid * 16 + glo;
        const int dst = ((((sel * 8 + gtile) * 4 + ktile) * 64) + lane) * 8 + j;
        const float v = sel ? Wa[gg * HID + kk] : Wd[gg * HID + kk];
        g_wfrag[dst] = f2bf(v);
    }

    const int n = tid;
    if (n < N_PTS) {
        const float px = spts[n * 3 + 0], py = spts[n * 3 + 1], pz = spts[n * 3 + 2];
        const float sn = s_arr[n];
        float bdist[9]; int bidx[9];
#pragma unroll
        for (int j = 0; j < 9; ++j) { bdist[j] = 1e30f; bidx[j] = -1; }
        for (int m = 0; m < N_PTS; ++m) {
            const float qx = spts[m * 3 + 0], qy = spts[m * 3 + 1], qz = spts[m * 3 + 2];
            float dot = __fmul_rn(px, qx);
            dot = fmaf(py, qy, dot);
            dot = fmaf(pz, qz, dot);
            float sq = __fsub_rn(__fadd_rn(sn, s_arr[m]), __fadd_rn(dot, dot));
            sq = fmaxf(sq, 0.0f);
            const float dm = __fsqrt_rn(sq);
            if (dm < bdist[8]) {                     // strict <: ties keep earlier index
                float cd = dm; int ci = m;
#pragma unroll
                for (int j = 0; j < 9; ++j) {
                    const bool less = cd < bdist[j];
                    const float td = less ? bdist[j] : cd;
                    const int   ti = less ? bidx[j]  : ci;
                    bdist[j] = less ? cd : bdist[j];
                    bidx[j]  = less ? ci : bidx[j];
                    cd = td; ci = ti;
                }
            }
        }
#pragma unroll
        for (int k = 0; k < KNN; ++k) {
            const int j = bidx[k + 1];
            g_refv[(n * KNN + k) * 3 + 0] = __fsub_rn(spts[j * 3 + 0], px);
            g_refv[(n * KNN + k) * 3 + 1] = __fsub_rn(spts[j * 3 + 1], py);
            g_refv[(n * KNN + k) * 3 + 2] = __fsub_rn(spts[j * 3 + 2], pz);
        }
    }
}

// -------- main: embeddings -> bf16 LDS tile -> MFMA GEMM + max-over-k -------
__global__ void __launch_bounds__(NTHREADS, 2) main_kernel(
    const float* __restrict__ points, const float* __restrict__ bd,
    const float* __restrict__ ba, float* __restrict__ out)
{
    __shared__ __align__(16) unsigned short sA[NROWS * HID];  // 36 KB bf16, XOR-swizzled
    __shared__ float sAidx[MT][KNN];
    __shared__ float sDidx[MT];
    __shared__ float sDiv[64];
    __shared__ float sRef[KNN][3];
    __shared__ float sPm[MT][3];
    __shared__ float sPn[3];

    const int t = threadIdx.x;
    const int n = blockIdx.y;
    const int m0 = blockIdx.x * MT;

    // ---- stage small data ----
    if (t < 64) sDiv[t] = expf(-0.14391156831212787f * (float)t); // 10000^(-t/64)
    if (t < 3) sPn[t] = points[n * 3 + t];
    if (t >= 64 && t < 64 + MT * 3) { int i = t - 64;  sPm[i / 3][i % 3] = points[m0 * 3 + i]; }
    if (t >= 128 && t < 128 + KNN * 3) { int i = t - 128; sRef[i / 3][i % 3] = g_refv[n * KNN * 3 + i]; }
    __syncthreads();

    // ---- geometry (r12-validated verbatim) ----
    if (t < MT) {
        const float qx = sPm[t][0], qy = sPm[t][1], qz = sPm[t][2];
        const float sn = __fadd_rn(__fadd_rn(__fmul_rn(sPn[0], sPn[0]), __fmul_rn(sPn[1], sPn[1])), __fmul_rn(sPn[2], sPn[2]));
        const float sm = __fadd_rn(__fadd_rn(__fmul_rn(qx, qx), __fmul_rn(qy, qy)), __fmul_rn(qz, qz));
        float dot = __fmul_rn(sPn[0], qx);
        dot = fmaf(sPn[1], qy, dot);
        dot = fmaf(sPn[2], qz, dot);
        float sq = __fsub_rn(__fadd_rn(sn, sm), __fadd_rn(dot, dot));
        sq = fmaxf(sq, 0.0f);
        sDidx[t] = __fdiv_rn(__fsqrt_rn(sq), 0.2f);   // dist / SIGMA_D
    }
    if (t < MT * KNN) {
        const int pair = t >> 3, k = t & 7;
        const float ax = sPm[pair][0] - sPn[0];
        const float ay = sPm[pair][1] - sPn[1];
        const float az = sPm[pair][2] - sPn[2];
        const float rx = sRef[k][0], ry = sRef[k][1], rz = sRef[k][2];
        const float cx = ry * az - rz * ay;
        const float cy = rz * ax - rx * az;
        const float cz = rx * ay - ry * ax;
        const float sv = sqrtf(cx * cx + cy * cy + cz * cz);
        const float cv = rx * ax + ry * ay + rz * az;
        float ang;
        if (sv == 0.0f) ang = 0.0f;          // degenerate -> 0, NEVER pi (r12 fix)
        else            ang = atan2f(sv, cv);
        sAidx[pair][k] = ang * 3.8197186342054885f;   // * 180/(15*pi)
    }
    __syncthreads();

    // ---- produce A tile: rows 0..15 = d(m); rows 16+k*16+m = a(m,k) ----
    // bf16 pair (sin,cos) per dword; byte addr XOR-swizzled by ((row&7)<<4).
    for (int idx = t; idx < NROWS * 64; idx += NTHREADS) {
        const int row = idx >> 6, i = idx & 63;
        float base;
        if (row < MT) base = sDidx[row];
        else { const int rr = row - MT; base = sAidx[rr & 15][rr >> 4]; }
        const float om = base * sDiv[i];
        const float rev0 = om * 0.15915494309189535f;     // radians -> revolutions
        const float rev = rev0 - rintf(rev0);             // [-0.5, 0.5]
        const float s = __builtin_amdgcn_sinf(rev);
        const float c = __builtin_amdgcn_cosf(rev);
        const unsigned int pack = (unsigned int)f2bf(s) | ((unsigned int)f2bf(c) << 16);
        int byte = row * 256 + i * 4;
        byte ^= (row & 7) << 4;
        *(unsigned int*)((char*)sA + byte) = pack;
    }
    __syncthreads();

    // ---- MFMA GEMM: wave w owns g-tile w (16 g's x 16 m's) ----
    const int wid  = t >> 6;
    const int lane = t & 63;
    const int rlo  = lane & 15;     // A row within tile / B col (g)
    const int kseg = lane >> 4;     // k sub-segment

    const short8_t* wf = (const short8_t*)g_wfrag;
    short8_t wdb[4], wab[4];
#pragma unroll
    for (int kt = 0; kt < 4; ++kt) {
        wdb[kt] = wf[(wid * 4 + kt) * 64 + lane];
        wab[kt] = wf[((8 + wid) * 4 + kt) * 64 + lane];
    }

    const char* sAb = (const char*)sA;
    f32x4_t accd = {0.f, 0.f, 0.f, 0.f};
#pragma unroll
    for (int kt = 0; kt < 4; ++kt) {
        int byte = rlo * 256 + kt * 64 + kseg * 16;
        byte ^= (rlo & 7) << 4;
        const short8_t af = *(const short8_t*)(sAb + byte);
        accd = __builtin_amdgcn_mfma_f32_16x16x32_bf16(af, wdb[kt], accd, 0, 0, 0);
    }

    f32x4_t amax = {0.f, 0.f, 0.f, 0.f};
#pragma unroll
    for (int k = 0; k < KNN; ++k) {
        f32x4_t acc = {0.f, 0.f, 0.f, 0.f};
        const int rowb = MT + k * 16 + rlo;
#pragma unroll
        for (int kt = 0; kt < 4; ++kt) {
            int byte = rowb * 256 + kt * 64 + kseg * 16;
            byte ^= (rowb & 7) << 4;
            const short8_t af = *(const short8_t*)(sAb + byte);
            acc = __builtin_amdgcn_mfma_f32_16x16x32_bf16(af, wab[kt], acc, 0, 0, 0);
        }
        if (k == 0) amax = acc;
        else {
            amax[0] = fmaxf(amax[0], acc[0]);
            amax[1] = fmaxf(amax[1], acc[1]);
            amax[2] = fmaxf(amax[2], acc[2]);
            amax[3] = fmaxf(amax[3], acc[3]);
        }
    }

    // ---- epilogue: C/D mapping col=lane&15 (g), row=(lane>>4)*4+reg (m) ----
    const int g = wid * 16 + rlo;
    const float bdv = bd[g];
    const float bav = ba[g];
#pragma unroll
    for (int r = 0; r < 4; ++r) {
        const int m = m0 + kseg * 4 + r;
        out[(n * N_PTS + m) * HID + g] = accd[r] + bdv + amax[r] + bav;
    }
}

extern "C" void kernel_launch(void* const* d_in, const int* in_sizes, int n_in,
                              void* d_out, int out_size, void* d_ws, size_t ws_size,
                              hipStream_t stream) {
    (void)in_sizes; (void)n_in; (void)out_size; (void)d_ws; (void)ws_size;
    const float* points = (const float*)d_in[0];
    const float* Wd     = (const float*)d_in[1];
    const float* bd     = (const float*)d_in[2];
    const float* Wa     = (const float*)d_in[3];
    const float* ba     = (const float*)d_in[4];
    float* out = (float*)d_out;

    prep_kernel<<<2, 256, 0, stream>>>(points, Wd, Wa);

    dim3 grid(N_PTS / MT, N_PTS);
    main_kernel<<<grid, NTHREADS, 0, stream>>>(points, bd, ba, out);
}

// Round 16
// 278.614 us; speedup vs baseline: 6.5229x; 1.1557x over previous
//
#include <hip/hip_runtime.h>
#include <math.h>

#define N_PTS 512
#define HID 128
#define KNN 8
#define MT 16               // m-tile per block
#define NTHREADS 512
#define NROWS 144           // 16 d rows + 128 a rows (8k x 16m)

typedef __attribute__((ext_vector_type(8))) short short8_t;   // 8 bf16 (4 VGPRs)
typedef __attribute__((ext_vector_type(4))) float f32x4_t;    // MFMA acc

// Persistent scratch in static device globals.
__device__ float g_refv[N_PTS * KNN * 3];          // [n][k][xyz] neighbor ref vectors
__device__ unsigned short g_wfrag[2 * 8 * 4 * 64 * 8]; // [sel][gtile][ktile][lane][j] bf16 B-frags

__device__ __forceinline__ unsigned short f2bf(float f) {   // RNE f32->bf16
    const unsigned int u = __float_as_uint(f);
    return (unsigned short)((u + 0x7FFFu + ((u >> 16) & 1u)) >> 16);
}

// -------- kNN: r12-EXACT serial arithmetic, one thread per n (8 x 64) -------
__global__ void __launch_bounds__(64) knn_kernel(const float* __restrict__ points)
{
    __shared__ float spts[N_PTS * 3];
    __shared__ float s_arr[N_PTS];
    const int t = threadIdx.x;
    const int n = blockIdx.x * 64 + t;

    for (int i = t; i < N_PTS * 3; i += 64) spts[i] = points[i];
    __syncthreads();
    for (int i = t; i < N_PTS; i += 64) {
        const float x = spts[i * 3 + 0], y = spts[i * 3 + 1], z = spts[i * 3 + 2];
        s_arr[i] = __fadd_rn(__fadd_rn(__fmul_rn(x, x), __fmul_rn(y, y)),
                             __fmul_rn(z, z));
    }
    __syncthreads();

    const float px = spts[n * 3 + 0], py = spts[n * 3 + 1], pz = spts[n * 3 + 2];
    const float sn = s_arr[n];
    float bdist[9]; int bidx[9];
#pragma unroll
    for (int j = 0; j < 9; ++j) { bdist[j] = 1e30f; bidx[j] = -1; }
    for (int m = 0; m < N_PTS; ++m) {
        const float qx = spts[m * 3 + 0], qy = spts[m * 3 + 1], qz = spts[m * 3 + 2];
        float dot = __fmul_rn(px, qx);
        dot = fmaf(py, qy, dot);
        dot = fmaf(pz, qz, dot);
        float sq = __fsub_rn(__fadd_rn(sn, s_arr[m]), __fadd_rn(dot, dot));
        sq = fmaxf(sq, 0.0f);
        const float dm = __fsqrt_rn(sq);
        if (dm < bdist[8]) {                     // strict <: ties keep earlier index
            float cd = dm; int ci = m;
#pragma unroll
            for (int j = 0; j < 9; ++j) {
                const bool less = cd < bdist[j];
                const float td = less ? bdist[j] : cd;
                const int   ti = less ? bidx[j]  : ci;
                bdist[j] = less ? cd : bdist[j];
                bidx[j]  = less ? ci : bidx[j];
                cd = td; ci = ti;
            }
        }
    }
#pragma unroll
    for (int k = 0; k < KNN; ++k) {
        const int j = bidx[k + 1];
        g_refv[(n * KNN + k) * 3 + 0] = __fsub_rn(spts[j * 3 + 0], px);
        g_refv[(n * KNN + k) * 3 + 1] = __fsub_rn(spts[j * 3 + 1], py);
        g_refv[(n * KNN + k) * 3 + 2] = __fsub_rn(spts[j * 3 + 2], pz);
    }
}

// -------- weight fragments: W[g][k] -> MFMA B-frag layout (bf16) ------------
__global__ void __launch_bounds__(512) wfrag_kernel(
    const float* __restrict__ Wd, const float* __restrict__ Wa)
{
    const int idx = blockIdx.x * 512 + threadIdx.x;   // 64 blocks -> 32768
    const int sel = idx >> 14;          // 0 = Wd, 1 = Wa
    const int rem = idx & 16383;
    const int gg = rem >> 7, kk = rem & 127;
    const int gtile = gg >> 4, glo = gg & 15;
    const int ktile = kk >> 5, kmid = (kk >> 3) & 3, j = kk & 7;
    const int lane = kmid * 16 + glo;
    const int dst = ((((sel * 8 + gtile) * 4 + ktile) * 64) + lane) * 8 + j;
    const float v = sel ? Wa[gg * HID + kk] : Wd[gg * HID + kk];
    g_wfrag[dst] = f2bf(v);
}

// -------- main: VERBATIM r13 (the PASSED binary's source) -------------------
__global__ void __launch_bounds__(NTHREADS, 2) main_kernel(
    const float* __restrict__ points, const float* __restrict__ bd,
    const float* __restrict__ ba, float* __restrict__ out)
{
    __shared__ __align__(16) unsigned short sA[NROWS * HID];  // 36 KB bf16, XOR-swizzled
    __shared__ float sAidx[MT][KNN];
    __shared__ float sDidx[MT];
    __shared__ float sDiv[64];
    __shared__ float sRef[KNN][3];
    __shared__ float sPm[MT][3];
    __shared__ float sPn[3];

    const int t = threadIdx.x;
    const int n = blockIdx.y;
    const int m0 = blockIdx.x * MT;

    // ---- stage small data ----
    if (t < 64) sDiv[t] = expf(-0.14391156831212787f * (float)t); // 10000^(-t/64)
    if (t < 3) sPn[t] = points[n * 3 + t];
    if (t >= 64 && t < 64 + MT * 3) { int i = t - 64;  sPm[i / 3][i % 3] = points[m0 * 3 + i]; }
    if (t >= 128 && t < 128 + KNN * 3) { int i = t - 128; sRef[i / 3][i % 3] = g_refv[n * KNN * 3 + i]; }
    __syncthreads();

    // ---- geometry (r12-validated verbatim) ----
    if (t < MT) {
        const float qx = sPm[t][0], qy = sPm[t][1], qz = sPm[t][2];
        const float sn = __fadd_rn(__fadd_rn(__fmul_rn(sPn[0], sPn[0]), __fmul_rn(sPn[1], sPn[1])), __fmul_rn(sPn[2], sPn[2]));
        const float sm = __fadd_rn(__fadd_rn(__fmul_rn(qx, qx), __fmul_rn(qy, qy)), __fmul_rn(qz, qz));
        float dot = __fmul_rn(sPn[0], qx);
        dot = fmaf(sPn[1], qy, dot);
        dot = fmaf(sPn[2], qz, dot);
        float sq = __fsub_rn(__fadd_rn(sn, sm), __fadd_rn(dot, dot));
        sq = fmaxf(sq, 0.0f);
        sDidx[t] = __fdiv_rn(__fsqrt_rn(sq), 0.2f);   // dist / SIGMA_D
    }
    if (t < MT * KNN) {
        const int pair = t >> 3, k = t & 7;
        const float ax = sPm[pair][0] - sPn[0];
        const float ay = sPm[pair][1] - sPn[1];
        const float az = sPm[pair][2] - sPn[2];
        const float rx = sRef[k][0], ry = sRef[k][1], rz = sRef[k][2];
        const float cx = ry * az - rz * ay;
        const float cy = rz * ax - rx * az;
        const float cz = rx * ay - ry * ax;
        const float sv = sqrtf(cx * cx + cy * cy + cz * cz);
        const float cv = rx * ax + ry * ay + rz * az;
        float ang;
        if (sv == 0.0f) ang = 0.0f;          // degenerate -> 0, NEVER pi (r12 fix)
        else            ang = atan2f(sv, cv);
        sAidx[pair][k] = ang * 3.8197186342054885f;   // * 180/(15*pi)
    }
    __syncthreads();

    // ---- produce A tile: rows 0..15 = d(m); rows 16+k*16+m = a(m,k) ----
    // bf16 pair (sin,cos) per dword; byte addr XOR-swizzled by ((row&7)<<4).
    for (int idx = t; idx < NROWS * 64; idx += NTHREADS) {
        const int row = idx >> 6, i = idx & 63;
        float base;
        if (row < MT) base = sDidx[row];
        else { const int rr = row - MT; base = sAidx[rr & 15][rr >> 4]; }
        const float om = base * sDiv[i];
        const float rev0 = om * 0.15915494309189535f;     // radians -> revolutions
        const float rev = rev0 - rintf(rev0);             // [-0.5, 0.5]
        const float s = __builtin_amdgcn_sinf(rev);
        const float c = __builtin_amdgcn_cosf(rev);
        const unsigned int pack = (unsigned int)f2bf(s) | ((unsigned int)f2bf(c) << 16);
        int byte = row * 256 + i * 4;
        byte ^= (row & 7) << 4;
        *(unsigned int*)((char*)sA + byte) = pack;
    }
    __syncthreads();

    // ---- MFMA GEMM: wave w owns g-tile w (16 g's x 16 m's) ----
    const int wid  = t >> 6;
    const int lane = t & 63;
    const int rlo  = lane & 15;     // A row within tile / B col (g)
    const int kseg = lane >> 4;     // k sub-segment

    const short8_t* wf = (const short8_t*)g_wfrag;
    short8_t wdb[4], wab[4];
#pragma unroll
    for (int kt = 0; kt < 4; ++kt) {
        wdb[kt] = wf[(wid * 4 + kt) * 64 + lane];
        wab[kt] = wf[((8 + wid) * 4 + kt) * 64 + lane];
    }

    const char* sAb = (const char*)sA;
    f32x4_t accd = {0.f, 0.f, 0.f, 0.f};
#pragma unroll
    for (int kt = 0; kt < 4; ++kt) {
        int byte = rlo * 256 + kt * 64 + kseg * 16;
        byte ^= (rlo & 7) << 4;
        const short8_t af = *(const short8_t*)(sAb + byte);
        accd = __builtin_amdgcn_mfma_f32_16x16x32_bf16(af, wdb[kt], accd, 0, 0, 0);
    }

    f32x4_t amax = {0.f, 0.f, 0.f, 0.f};
#pragma unroll
    for (int k = 0; k < KNN; ++k) {
        f32x4_t acc = {0.f, 0.f, 0.f, 0.f};
        const int rowb = MT + k * 16 + rlo;
#pragma unroll
        for (int kt = 0; kt < 4; ++kt) {
            int byte = rowb * 256 + kt * 64 + kseg * 16;
            byte ^= (rowb & 7) << 4;
            const short8_t af = *(const short8_t*)(sAb + byte);
            acc = __builtin_amdgcn_mfma_f32_16x16x32_bf16(af, wab[kt], acc, 0, 0, 0);
        }
        if (k == 0) amax = acc;
        else {
            amax[0] = fmaxf(amax[0], acc[0]);
            amax[1] = fmaxf(amax[1], acc[1]);
            amax[2] = fmaxf(amax[2], acc[2]);
            amax[3] = fmaxf(amax[3], acc[3]);
        }
    }

    // ---- epilogue: C/D mapping col=lane&15 (g), row=(lane>>4)*4+reg (m) ----
    const int g = wid * 16 + rlo;
    const float bdv = bd[g];
    const float bav = ba[g];
#pragma unroll
    for (int r = 0; r < 4; ++r) {
        const int m = m0 + kseg * 4 + r;
        out[(n * N_PTS + m) * HID + g] = accd[r] + bdv + amax[r] + bav;
    }
}

extern "C" void kernel_launch(void* const* d_in, const int* in_sizes, int n_in,
                              void* d_out, int out_size, void* d_ws, size_t ws_size,
                              hipStream_t stream) {
    (void)in_sizes; (void)n_in; (void)out_size; (void)d_ws; (void)ws_size;
    const float* points = (const float*)d_in[0];
    const float* Wd     = (const float*)d_in[1];
    const float* bd     = (const float*)d_in[2];
    const float* Wa     = (const float*)d_in[3];
    const float* ba     = (const float*)d_in[4];
    float* out = (float*)d_out;

    knn_kernel<<<8, 64, 0, stream>>>(points);
    wfrag_kernel<<<64, 512, 0, stream>>>(Wd, Wa);

    dim3 grid(N_PTS / MT, N_PTS);
    main_kernel<<<grid, NTHREADS, 0, stream>>>(points, bd, ba, out);
}

// Round 17
// 228.909 us; speedup vs baseline: 7.9393x; 1.2171x over previous
//
#include <hip/hip_runtime.h>
#include <math.h>

#define N_PTS 512
#define HID 128
#define KNN 8
#define MT 16               // m-tile per block
#define NTHREADS 512
#define NROWS 144           // 16 d rows + 128 a rows (8k x 16m)

typedef __attribute__((ext_vector_type(8))) short short8_t;   // 8 bf16 (4 VGPRs)
typedef __attribute__((ext_vector_type(4))) float f32x4_t;    // MFMA acc

// Persistent scratch in static device globals.
__device__ float g_refv[N_PTS * KNN * 3];          // [n][k][xyz] neighbor ref vectors
__device__ unsigned short g_wfrag[2 * 8 * 4 * 64 * 8]; // [sel][gtile][ktile][lane][j] bf16 B-frags

__device__ __forceinline__ unsigned short f2bf(float f) {   // RNE f32->bf16
    const unsigned int u = __float_as_uint(f);
    return (unsigned short)((u + 0x7FFFu + ((u >> 16) & 1u)) >> 16);
}

// -------- kNN: r12-EXACT serial arithmetic, one thread per n (8 x 64) -------
__global__ void __launch_bounds__(64) knn_kernel(const float* __restrict__ points)
{
    __shared__ float spts[N_PTS * 3];
    __shared__ float s_arr[N_PTS];
    const int t = threadIdx.x;
    const int n = blockIdx.x * 64 + t;

    for (int i = t; i < N_PTS * 3; i += 64) spts[i] = points[i];
    __syncthreads();
    for (int i = t; i < N_PTS; i += 64) {
        const float x = spts[i * 3 + 0], y = spts[i * 3 + 1], z = spts[i * 3 + 2];
        s_arr[i] = __fadd_rn(__fadd_rn(__fmul_rn(x, x), __fmul_rn(y, y)),
                             __fmul_rn(z, z));
    }
    __syncthreads();

    const float px = spts[n * 3 + 0], py = spts[n * 3 + 1], pz = spts[n * 3 + 2];
    const float sn = s_arr[n];
    float bdist[9]; int bidx[9];
#pragma unroll
    for (int j = 0; j < 9; ++j) { bdist[j] = 1e30f; bidx[j] = -1; }
    for (int m = 0; m < N_PTS; ++m) {
        const float qx = spts[m * 3 + 0], qy = spts[m * 3 + 1], qz = spts[m * 3 + 2];
        float dot = __fmul_rn(px, qx);
        dot = fmaf(py, qy, dot);
        dot = fmaf(pz, qz, dot);
        float sq = __fsub_rn(__fadd_rn(sn, s_arr[m]), __fadd_rn(dot, dot));
        sq = fmaxf(sq, 0.0f);
        const float dm = __fsqrt_rn(sq);
        if (dm < bdist[8]) {                     // strict <: ties keep earlier index
            float cd = dm; int ci = m;
#pragma unroll
            for (int j = 0; j < 9; ++j) {
                const bool less = cd < bdist[j];
                const float td = less ? bdist[j] : cd;
                const int   ti = less ? bidx[j]  : ci;
                bdist[j] = less ? cd : bdist[j];
                bidx[j]  = less ? ci : bidx[j];
                cd = td; ci = ti;
            }
        }
    }
#pragma unroll
    for (int k = 0; k < KNN; ++k) {
        const int j = bidx[k + 1];
        g_refv[(n * KNN + k) * 3 + 0] = __fsub_rn(spts[j * 3 + 0], px);
        g_refv[(n * KNN + k) * 3 + 1] = __fsub_rn(spts[j * 3 + 1], py);
        g_refv[(n * KNN + k) * 3 + 2] = __fsub_rn(spts[j * 3 + 2], pz);
    }
}

// -------- weight fragments: W[g][k] -> MFMA B-frag layout (bf16) ------------
__global__ void __launch_bounds__(512) wfrag_kernel(
    const float* __restrict__ Wd, const float* __restrict__ Wa)
{
    const int idx = blockIdx.x * 512 + threadIdx.x;   // 64 blocks -> 32768
    const int sel = idx >> 14;          // 0 = Wd, 1 = Wa
    const int rem = idx & 16383;
    const int gg = rem >> 7, kk = rem & 127;
    const int gtile = gg >> 4, glo = gg & 15;
    const int ktile = kk >> 5, kmid = (kk >> 3) & 3, j = kk & 7;
    const int lane = kmid * 16 + glo;
    const int dst = ((((sel * 8 + gtile) * 4 + ktile) * 64) + lane) * 8 + j;
    const float v = sel ? Wa[gg * HID + kk] : Wd[gg * HID + kk];
    g_wfrag[dst] = f2bf(v);
}

// -------- main: r16 GEMM/geometry + lean fill (sBase, imm-offset, perm-pack) -
__global__ void __launch_bounds__(NTHREADS, 2) main_kernel(
    const float* __restrict__ points, const float* __restrict__ bd,
    const float* __restrict__ ba, float* __restrict__ out)
{
    __shared__ __align__(16) unsigned short sA[NROWS * HID];  // 36 KB bf16, XOR-swizzled
    __shared__ float sBase[NROWS];   // [0..15]=d_idx(m); [16+k*16+m]=a_idx(m,k)
    __shared__ float sDiv[64];
    __shared__ float sRef[KNN][3];
    __shared__ float sPm[MT][3];
    __shared__ float sPn[3];

    const int t = threadIdx.x;
    const int n = blockIdx.y;
    const int m0 = blockIdx.x * MT;

    // ---- stage small data ----
    if (t < 64) sDiv[t] = expf(-0.14391156831212787f * (float)t); // 10000^(-t/64)
    if (t < 3) sPn[t] = points[n * 3 + t];
    if (t >= 64 && t < 64 + MT * 3) { int i = t - 64;  sPm[i / 3][i % 3] = points[m0 * 3 + i]; }
    if (t >= 128 && t < 128 + KNN * 3) { int i = t - 128; sRef[i / 3][i % 3] = g_refv[n * KNN * 3 + i]; }
    __syncthreads();

    // ---- geometry (r12-validated arithmetic, writes into flat sBase) ----
    if (t < MT) {
        const float qx = sPm[t][0], qy = sPm[t][1], qz = sPm[t][2];
        const float sn = __fadd_rn(__fadd_rn(__fmul_rn(sPn[0], sPn[0]), __fmul_rn(sPn[1], sPn[1])), __fmul_rn(sPn[2], sPn[2]));
        const float sm = __fadd_rn(__fadd_rn(__fmul_rn(qx, qx), __fmul_rn(qy, qy)), __fmul_rn(qz, qz));
        float dot = __fmul_rn(sPn[0], qx);
        dot = fmaf(sPn[1], qy, dot);
        dot = fmaf(sPn[2], qz, dot);
        float sq = __fsub_rn(__fadd_rn(sn, sm), __fadd_rn(dot, dot));
        sq = fmaxf(sq, 0.0f);
        sBase[t] = __fdiv_rn(__fsqrt_rn(sq), 0.2f);   // dist / SIGMA_D
    }
    if (t < MT * KNN) {
        const int pair = t >> 3, k = t & 7;
        const float ax = sPm[pair][0] - sPn[0];
        const float ay = sPm[pair][1] - sPn[1];
        const float az = sPm[pair][2] - sPn[2];
        const float rx = sRef[k][0], ry = sRef[k][1], rz = sRef[k][2];
        const float cx = ry * az - rz * ay;
        const float cy = rz * ax - rx * az;
        const float cz = rx * ay - ry * ax;
        const float sv = sqrtf(cx * cx + cy * cy + cz * cz);
        const float cv = rx * ax + ry * ay + rz * az;
        float ang;
        if (sv == 0.0f) ang = 0.0f;          // degenerate -> 0, NEVER pi (r12 fix)
        else            ang = atan2f(sv, cv);
        // row = 16 + k*16 + pair  (matches fill's base = sAidx[(row-16)&15][(row-16)>>4])
        sBase[MT + k * 16 + pair] = ang * 3.8197186342054885f;   // * 180/(15*pi)
    }
    __syncthreads();

    // ---- A tile fill: value-arithmetic identical to r16 except trunc-pack ----
    // thread: fixed freq i = t&63, rows r0+8*it; all addresses thread-constant
    // base + compile-time immediates (fold into ds offsets).
    {
        const int r0 = t >> 6;              // 0..7
        const int i  = t & 63;
        const float dv = sDiv[i];           // same value/read as r16's per-element read
        const float* const rd = &sBase[r0];
        char* const wr = (char*)sA + ((unsigned)((i * 4) ^ (r0 << 4)) + (unsigned)r0 * 256);
#pragma unroll
        for (int it = 0; it < 18; ++it) {
            const float base = rd[it * 8];                    // sBase[r0 + 8*it]
            const float om   = base * dv;                     // r16 op order
            const float rev0 = om * 0.15915494309189535f;     // radians -> revolutions
            const float rev  = rev0 - rintf(rev0);            // [-0.5, 0.5]
            const float s = __builtin_amdgcn_sinf(rev);
            const float c = __builtin_amdgcn_cosf(rev);
            // pack = trunc(s) | trunc(c)<<16 via one byte-perm (bytes {c3,c2,s3,s2})
            const unsigned int pack = __builtin_amdgcn_perm(
                __float_as_uint(c), __float_as_uint(s), 0x07060302u);
            *(unsigned int*)(wr + it * 2048) = pack;          // row*256 folded: r0*256 + it*2048
        }
    }
    __syncthreads();

    // ---- MFMA GEMM: VERBATIM r16 ----
    const int wid  = t >> 6;
    const int lane = t & 63;
    const int rlo  = lane & 15;     // A row within tile / B col (g)
    const int kseg = lane >> 4;     // k sub-segment

    const short8_t* wf = (const short8_t*)g_wfrag;
    short8_t wdb[4], wab[4];
#pragma unroll
    for (int kt = 0; kt < 4; ++kt) {
        wdb[kt] = wf[(wid * 4 + kt) * 64 + lane];
        wab[kt] = wf[((8 + wid) * 4 + kt) * 64 + lane];
    }

    const char* sAb = (const char*)sA;
    f32x4_t accd = {0.f, 0.f, 0.f, 0.f};
#pragma unroll
    for (int kt = 0; kt < 4; ++kt) {
        int byte = rlo * 256 + kt * 64 + kseg * 16;
        byte ^= (rlo & 7) << 4;
        const short8_t af = *(const short8_t*)(sAb + byte);
        accd = __builtin_amdgcn_mfma_f32_16x16x32_bf16(af, wdb[kt], accd, 0, 0, 0);
    }

    f32x4_t amax = {0.f, 0.f, 0.f, 0.f};
#pragma unroll
    for (int k = 0; k < KNN; ++k) {
        f32x4_t acc = {0.f, 0.f, 0.f, 0.f};
        const int rowb = MT + k * 16 + rlo;
#pragma unroll
        for (int kt = 0; kt < 4; ++kt) {
            int byte = rowb * 256 + kt * 64 + kseg * 16;
            byte ^= (rowb & 7) << 4;
            const short8_t af = *(const short8_t*)(sAb + byte);
            acc = __builtin_amdgcn_mfma_f32_16x16x32_bf16(af, wab[kt], acc, 0, 0, 0);
        }
        if (k == 0) amax = acc;
        else {
            amax[0] = fmaxf(amax[0], acc[0]);
            amax[1] = fmaxf(amax[1], acc[1]);
            amax[2] = fmaxf(amax[2], acc[2]);
            amax[3] = fmaxf(amax[3], acc[3]);
        }
    }

    // ---- epilogue: C/D mapping col=lane&15 (g), row=(lane>>4)*4+reg (m) ----
    const int g = wid * 16 + rlo;
    const float bdv = bd[g];
    const float bav = ba[g];
#pragma unroll
    for (int r = 0; r < 4; ++r) {
        const int m = m0 + kseg * 4 + r;
        out[(n * N_PTS + m) * HID + g] = accd[r] + bdv + amax[r] + bav;
    }
}

extern "C" void kernel_launch(void* const* d_in, const int* in_sizes, int n_in,
                              void* d_out, int out_size, void* d_ws, size_t ws_size,
                              hipStream_t stream) {
    (void)in_sizes; (void)n_in; (void)out_size; (void)d_ws; (void)ws_size;
    const float* points = (const float*)d_in[0];
    const float* Wd     = (const float*)d_in[1];
    const float* bd     = (const float*)d_in[2];
    const float* Wa     = (const float*)d_in[3];
    const float* ba     = (const float*)d_in[4];
    float* out = (float*)d_out;

    knn_kernel<<<8, 64, 0, stream>>>(points);
    wfrag_kernel<<<64, 512, 0, stream>>>(Wd, Wa);

    dim3 grid(N_PTS / MT, N_PTS);
    main_kernel<<<grid, NTHREADS, 0, stream>>>(points, bd, ba, out);
}

// Round 18
// 125.397 us; speedup vs baseline: 14.4929x; 1.8255x over previous
//
#include <hip/hip_runtime.h>
#include <math.h>

#define N_PTS 512
#define HID 128
#define KNN 8
#define MT 16               // m-tile per block
#define NTHREADS 512
#define NROWS 144           // 16 d rows + 128 a rows (8k x 16m)

typedef __attribute__((ext_vector_type(8))) short short8_t;   // 8 bf16 (4 VGPRs)
typedef __attribute__((ext_vector_type(4))) float f32x4_t;    // MFMA acc

// Persistent scratch in static device globals.
__device__ float g_refv[N_PTS * KNN * 3];          // [n][k][xyz] neighbor ref vectors
__device__ unsigned short g_wfrag[2 * 8 * 4 * 64 * 8]; // [sel][gtile][ktile][lane][j] bf16 B-frags

__device__ __forceinline__ unsigned short f2bf(float f) {   // RNE f32->bf16
    const unsigned int u = __float_as_uint(f);
    return (unsigned short)((u + 0x7FFFu + ((u >> 16) & 1u)) >> 16);
}

// -------- prep: fused wave-kNN (exonerated by r14/r15 bisection) + wfrag ----
// One block (64 lanes) per point n. kNN keys pack (sq_as_uint<<32)|m: monotone
// for sq>=0, ties -> smaller m (top_k semantics). Set-equivalence to the
// r12-validated serial version is guaranteed by the r8 gap census (min
// rank-8/9 gap 7e-5 >> direct-diff f32 noise ~1e-7) and was confirmed
// empirically by the bit-identical r14/r15 failure signatures.
__global__ void __launch_bounds__(64) prep_kernel(
    const float* __restrict__ points, const float* __restrict__ Wd,
    const float* __restrict__ Wa)
{
    __shared__ float spts[N_PTS * 3];
    const int lane = threadIdx.x;       // 0..63
    const int n = blockIdx.x;           // 0..511

    for (int i = lane; i < N_PTS * 3; i += 64) spts[i] = points[i];
    __syncthreads();

    // ---- weight fragments: this block converts 64 elements (512x64 = 32768) ----
    {
        const int idx = n * 64 + lane;
        const int sel = idx >> 14;          // 0 = Wd, 1 = Wa
        const int rem = idx & 16383;
        const int gg = rem >> 7, kk = rem & 127;
        const int gtile = gg >> 4, glo = gg & 15;
        const int ktile = kk >> 5, kmid = (kk >> 3) & 3, j = kk & 7;
        const int fl = kmid * 16 + glo;
        const int dst = ((((sel * 8 + gtile) * 4 + ktile) * 64) + fl) * 8 + j;
        const float v = sel ? Wa[gg * HID + kk] : Wd[gg * HID + kk];
        g_wfrag[dst] = f2bf(v);
    }

    // ---- kNN: 8 candidates per lane, 9 shfl-min rounds ----
    const float px = spts[n * 3 + 0], py = spts[n * 3 + 1], pz = spts[n * 3 + 2];
    unsigned long long keys[8];
#pragma unroll
    for (int j = 0; j < 8; ++j) {
        const int m = lane * 8 + j;
        const float dx = spts[m * 3 + 0] - px;
        const float dy = spts[m * 3 + 1] - py;
        const float dz = spts[m * 3 + 2] - pz;
        const float sq = dx * dx + dy * dy + dz * dz;
        keys[j] = ((unsigned long long)__float_as_uint(sq) << 32) | (unsigned)m;
    }
    // round 0 removes self (sq == +0 exactly); rounds 1..8 emit the 8 neighbors
    for (int r = 0; r < 9; ++r) {
        unsigned long long lmin = ~0ULL;
#pragma unroll
        for (int j = 0; j < 8; ++j) lmin = keys[j] < lmin ? keys[j] : lmin;
        for (int s = 1; s < 64; s <<= 1) {
            const unsigned long long o = __shfl_xor(lmin, s, 64);
            lmin = o < lmin ? o : lmin;
        }
        const int mwin = (int)(unsigned)lmin;
        if ((mwin >> 3) == lane) keys[mwin & 7] = ~0ULL;   // mark taken
        if (r > 0 && lane == 0) {
            const int k = r - 1;
            g_refv[(n * KNN + k) * 3 + 0] = __fsub_rn(spts[mwin * 3 + 0], px);
            g_refv[(n * KNN + k) * 3 + 1] = __fsub_rn(spts[mwin * 3 + 1], py);
            g_refv[(n * KNN + k) * 3 + 2] = __fsub_rn(spts[mwin * 3 + 2], pz);
        }
    }
}

// -------- main: r17-PASS structure + fract reduction + folded freq ----------
__global__ void __launch_bounds__(NTHREADS, 2) main_kernel(
    const float* __restrict__ points, const float* __restrict__ bd,
    const float* __restrict__ ba, float* __restrict__ out)
{
    __shared__ __align__(16) unsigned short sA[NROWS * HID];  // 36 KB bf16, XOR-swizzled
    __shared__ float sBase[NROWS];   // [0..15]=d_idx(m); [16+k*16+m]=a_idx(m,k)
    __shared__ float sRef[KNN][3];
    __shared__ float sPm[MT][3];
    __shared__ float sPn[3];

    const int t = threadIdx.x;
    const int n = blockIdx.y;
    const int m0 = blockIdx.x * MT;

    // per-thread frequency with 1/2pi folded: dv2 = 10000^(-i/64) / 2pi
    const int r0 = t >> 6;              // wave id = row stripe
    const int i  = t & 63;              // frequency index
    const float dv2 = expf(-0.14391156831212787f * (float)i) * 0.15915494309189535f;

    // ---- stage small data ----
    if (t < 3) sPn[t] = points[n * 3 + t];
    if (t >= 64 && t < 64 + MT * 3) { int q = t - 64;  sPm[q / 3][q % 3] = points[m0 * 3 + q]; }
    if (t >= 128 && t < 128 + KNN * 3) { int q = t - 128; sRef[q / 3][q % 3] = g_refv[n * KNN * 3 + q]; }
    __syncthreads();

    // ---- geometry (r12-validated arithmetic, writes into flat sBase) ----
    if (t < MT) {
        const float qx = sPm[t][0], qy = sPm[t][1], qz = sPm[t][2];
        const float sn = __fadd_rn(__fadd_rn(__fmul_rn(sPn[0], sPn[0]), __fmul_rn(sPn[1], sPn[1])), __fmul_rn(sPn[2], sPn[2]));
        const float sm = __fadd_rn(__fadd_rn(__fmul_rn(qx, qx), __fmul_rn(qy, qy)), __fmul_rn(qz, qz));
        float dot = __fmul_rn(sPn[0], qx);
        dot = fmaf(sPn[1], qy, dot);
        dot = fmaf(sPn[2], qz, dot);
        float sq = __fsub_rn(__fadd_rn(sn, sm), __fadd_rn(dot, dot));
        sq = fmaxf(sq, 0.0f);
        sBase[t] = __fdiv_rn(__fsqrt_rn(sq), 0.2f);   // dist / SIGMA_D
    }
    if (t < MT * KNN) {
        const int pair = t >> 3, k = t & 7;
        const float ax = sPm[pair][0] - sPn[0];
        const float ay = sPm[pair][1] - sPn[1];
        const float az = sPm[pair][2] - sPn[2];
        const float rx = sRef[k][0], ry = sRef[k][1], rz = sRef[k][2];
        const float cx = ry * az - rz * ay;
        const float cy = rz * ax - rx * az;
        const float cz = rx * ay - ry * ax;
        const float sv = sqrtf(cx * cx + cy * cy + cz * cz);
        const float cv = rx * ax + ry * ay + rz * az;
        float ang;
        if (sv == 0.0f) ang = 0.0f;          // degenerate -> 0, NEVER pi (r12 fix)
        else            ang = atan2f(sv, cv);
        sBase[MT + k * 16 + pair] = ang * 3.8197186342054885f;   // * 180/(15*pi)
    }
    __syncthreads();

    // ---- A tile fill: thread = (freq i, row stripe r0); imm-offset LDS ----
    {
        const float* const rd = &sBase[r0];
        char* const wr = (char*)sA + ((unsigned)((i * 4) ^ (r0 << 4)) + (unsigned)r0 * 256);
#pragma unroll
        for (int it = 0; it < 18; ++it) {
            const float base = rd[it * 8];                    // sBase[r0 + 8*it]
            const float rev0 = base * dv2;                    // radians->revs folded
            const float rev  = rev0 - floorf(rev0);           // v_fract: [0,1) revs
            const float s = __builtin_amdgcn_sinf(rev);
            const float c = __builtin_amdgcn_cosf(rev);
            // pack = trunc(s) | trunc(c)<<16 via one byte-perm
            const unsigned int pack = __builtin_amdgcn_perm(
                __float_as_uint(c), __float_as_uint(s), 0x07060302u);
            *(unsigned int*)(wr + it * 2048) = pack;          // row*256: r0*256 + it*2048
        }
    }
    __syncthreads();

    // ---- MFMA GEMM: VERBATIM r16/r17 ----
    const int wid  = t >> 6;
    const int lane = t & 63;
    const int rlo  = lane & 15;     // A row within tile / B col (g)
    const int kseg = lane >> 4;     // k sub-segment

    const short8_t* wf = (const short8_t*)g_wfrag;
    short8_t wdb[4], wab[4];
#pragma unroll
    for (int kt = 0; kt < 4; ++kt) {
        wdb[kt] = wf[(wid * 4 + kt) * 64 + lane];
        wab[kt] = wf[((8 + wid) * 4 + kt) * 64 + lane];
    }

    const char* sAb = (const char*)sA;
    f32x4_t accd = {0.f, 0.f, 0.f, 0.f};
#pragma unroll
    for (int kt = 0; kt < 4; ++kt) {
        int byte = rlo * 256 + kt * 64 + kseg * 16;
        byte ^= (rlo & 7) << 4;
        const short8_t af = *(const short8_t*)(sAb + byte);
        accd = __builtin_amdgcn_mfma_f32_16x16x32_bf16(af, wdb[kt], accd, 0, 0, 0);
    }

    f32x4_t amax = {0.f, 0.f, 0.f, 0.f};
#pragma unroll
    for (int k = 0; k < KNN; ++k) {
        f32x4_t acc = {0.f, 0.f, 0.f, 0.f};
        const int rowb = MT + k * 16 + rlo;
#pragma unroll
        for (int kt = 0; kt < 4; ++kt) {
            int byte = rowb * 256 + kt * 64 + kseg * 16;
            byte ^= (rowb & 7) << 4;
            const short8_t af = *(const short8_t*)(sAb + byte);
            acc = __builtin_amdgcn_mfma_f32_16x16x32_bf16(af, wab[kt], acc, 0, 0, 0);
        }
        if (k == 0) amax = acc;
        else {
            amax[0] = fmaxf(amax[0], acc[0]);
            amax[1] = fmaxf(amax[1], acc[1]);
            amax[2] = fmaxf(amax[2], acc[2]);
            amax[3] = fmaxf(amax[3], acc[3]);
        }
    }

    // ---- epilogue: C/D mapping col=lane&15 (g), row=(lane>>4)*4+reg (m) ----
    const int g = wid * 16 + rlo;
    const float bdv = bd[g];
    const float bav = ba[g];
#pragma unroll
    for (int r = 0; r < 4; ++r) {
        const int m = m0 + kseg * 4 + r;
        out[(n * N_PTS + m) * HID + g] = accd[r] + bdv + amax[r] + bav;
    }
}

extern "C" void kernel_launch(void* const* d_in, const int* in_sizes, int n_in,
                              void* d_out, int out_size, void* d_ws, size_t ws_size,
                              hipStream_t stream) {
    (void)in_sizes; (void)n_in; (void)out_size; (void)d_ws; (void)ws_size;
    const float* points = (const float*)d_in[0];
    const float* Wd     = (const float*)d_in[1];
    const float* bd     = (const float*)d_in[2];
    const float* Wa     = (const float*)d_in[3];
    const float* ba     = (const float*)d_in[4];
    float* out = (float*)d_out;

    prep_kernel<<<N_PTS, 64, 0, stream>>>(points, Wd, Wa);

    dim3 grid(N_PTS / MT, N_PTS);
    main_kernel<<<grid, NTHREADS, 0, stream>>>(points, bd, ba, out);
}

// Round 19
// 113.088 us; speedup vs baseline: 16.0704x; 1.1088x over previous
//
#include <hip/hip_runtime.h>
#include <math.h>

#define N_PTS 512
#define HID 128
#define KNN 8
#define MT 16               // m-tile per block
#define NTHREADS 256        // 4 waves; each wave covers 2 g-tiles
#define NROWS 144           // 16 d rows + 128 a rows (8k x 16m)

typedef __attribute__((ext_vector_type(8))) short short8_t;   // 8 bf16 (4 VGPRs)
typedef __attribute__((ext_vector_type(4))) float f32x4_t;    // MFMA acc

// Persistent scratch in static device globals.
__device__ float g_refv[N_PTS * KNN * 3];          // [n][k][xyz] neighbor ref vectors
__device__ unsigned short g_wfrag[2 * 8 * 4 * 64 * 8]; // [sel][gtile][ktile][lane][j] bf16 B-frags

__device__ __forceinline__ unsigned short f2bf(float f) {   // RNE f32->bf16
    const unsigned int u = __float_as_uint(f);
    return (unsigned short)((u + 0x7FFFu + ((u >> 16) & 1u)) >> 16);
}

// -------- prep: fused wave-kNN + wfrag (VERBATIM r18-PASS) ------------------
__global__ void __launch_bounds__(64) prep_kernel(
    const float* __restrict__ points, const float* __restrict__ Wd,
    const float* __restrict__ Wa)
{
    __shared__ float spts[N_PTS * 3];
    const int lane = threadIdx.x;       // 0..63
    const int n = blockIdx.x;           // 0..511

    for (int i = lane; i < N_PTS * 3; i += 64) spts[i] = points[i];
    __syncthreads();

    // ---- weight fragments: this block converts 64 elements (512x64 = 32768) ----
    {
        const int idx = n * 64 + lane;
        const int sel = idx >> 14;          // 0 = Wd, 1 = Wa
        const int rem = idx & 16383;
        const int gg = rem >> 7, kk = rem & 127;
        const int gtile = gg >> 4, glo = gg & 15;
        const int ktile = kk >> 5, kmid = (kk >> 3) & 3, j = kk & 7;
        const int fl = kmid * 16 + glo;
        const int dst = ((((sel * 8 + gtile) * 4 + ktile) * 64) + fl) * 8 + j;
        const float v = sel ? Wa[gg * HID + kk] : Wd[gg * HID + kk];
        g_wfrag[dst] = f2bf(v);
    }

    // ---- kNN: 8 candidates per lane, 9 shfl-min rounds ----
    const float px = spts[n * 3 + 0], py = spts[n * 3 + 1], pz = spts[n * 3 + 2];
    unsigned long long keys[8];
#pragma unroll
    for (int j = 0; j < 8; ++j) {
        const int m = lane * 8 + j;
        const float dx = spts[m * 3 + 0] - px;
        const float dy = spts[m * 3 + 1] - py;
        const float dz = spts[m * 3 + 2] - pz;
        const float sq = dx * dx + dy * dy + dz * dz;
        keys[j] = ((unsigned long long)__float_as_uint(sq) << 32) | (unsigned)m;
    }
    // round 0 removes self (sq == +0 exactly); rounds 1..8 emit the 8 neighbors
    for (int r = 0; r < 9; ++r) {
        unsigned long long lmin = ~0ULL;
#pragma unroll
        for (int j = 0; j < 8; ++j) lmin = keys[j] < lmin ? keys[j] : lmin;
        for (int s = 1; s < 64; s <<= 1) {
            const unsigned long long o = __shfl_xor(lmin, s, 64);
            lmin = o < lmin ? o : lmin;
        }
        const int mwin = (int)(unsigned)lmin;
        if ((mwin >> 3) == lane) keys[mwin & 7] = ~0ULL;   // mark taken
        if (r > 0 && lane == 0) {
            const int k = r - 1;
            g_refv[(n * KNN + k) * 3 + 0] = __fsub_rn(spts[mwin * 3 + 0], px);
            g_refv[(n * KNN + k) * 3 + 1] = __fsub_rn(spts[mwin * 3 + 1], py);
            g_refv[(n * KNN + k) * 3 + 2] = __fsub_rn(spts[mwin * 3 + 2], pz);
        }
    }
}

// -------- main: 4 waves x 2 g-tiles (A-LDS traffic halved vs r18) -----------
__global__ void __launch_bounds__(NTHREADS, 3) main_kernel(
    const float* __restrict__ points, const float* __restrict__ bd,
    const float* __restrict__ ba, float* __restrict__ out)
{
    __shared__ __align__(16) unsigned short sA[NROWS * HID];  // 36 KB bf16, XOR-swizzled
    __shared__ float sBase[NROWS];   // [0..15]=d_idx(m); [16+k*16+m]=a_idx(m,k)
    __shared__ float sRef[KNN][3];
    __shared__ float sPm[MT][3];
    __shared__ float sPn[3];

    const int t = threadIdx.x;
    const int n = blockIdx.y;
    const int m0 = blockIdx.x * MT;

    const int r0 = t >> 6;              // wave id (0..3) = row stripe
    const int i  = t & 63;              // frequency index
    // per-thread frequency with 1/2pi folded: dv2 = 10000^(-i/64) / 2pi
    const float dv2 = expf(-0.14391156831212787f * (float)i) * 0.15915494309189535f;

    // ---- stage small data ----
    if (t < 3) sPn[t] = points[n * 3 + t];
    if (t >= 64 && t < 64 + MT * 3) { int q = t - 64;  sPm[q / 3][q % 3] = points[m0 * 3 + q]; }
    if (t >= 128 && t < 128 + KNN * 3) { int q = t - 128; sRef[q / 3][q % 3] = g_refv[n * KNN * 3 + q]; }
    __syncthreads();

    // ---- geometry (r12-validated arithmetic, writes into flat sBase) ----
    if (t < MT) {
        const float qx = sPm[t][0], qy = sPm[t][1], qz = sPm[t][2];
        const float sn = __fadd_rn(__fadd_rn(__fmul_rn(sPn[0], sPn[0]), __fmul_rn(sPn[1], sPn[1])), __fmul_rn(sPn[2], sPn[2]));
        const float sm = __fadd_rn(__fadd_rn(__fmul_rn(qx, qx), __fmul_rn(qy, qy)), __fmul_rn(qz, qz));
        float dot = __fmul_rn(sPn[0], qx);
        dot = fmaf(sPn[1], qy, dot);
        dot = fmaf(sPn[2], qz, dot);
        float sq = __fsub_rn(__fadd_rn(sn, sm), __fadd_rn(dot, dot));
        sq = fmaxf(sq, 0.0f);
        sBase[t] = __fdiv_rn(__fsqrt_rn(sq), 0.2f);   // dist / SIGMA_D
    }
    if (t < MT * KNN) {
        const int pair = t >> 3, k = t & 7;
        const float ax = sPm[pair][0] - sPn[0];
        const float ay = sPm[pair][1] - sPn[1];
        const float az = sPm[pair][2] - sPn[2];
        const float rx = sRef[k][0], ry = sRef[k][1], rz = sRef[k][2];
        const float cx = ry * az - rz * ay;
        const float cy = rz * ax - rx * az;
        const float cz = rx * ay - ry * ax;
        const float sv = sqrtf(cx * cx + cy * cy + cz * cz);
        const float cv = rx * ax + ry * ay + rz * az;
        float ang;
        if (sv == 0.0f) ang = 0.0f;          // degenerate -> 0, NEVER pi (r12 fix)
        else            ang = atan2f(sv, cv);
        sBase[MT + k * 16 + pair] = ang * 3.8197186342054885f;   // * 180/(15*pi)
    }
    __syncthreads();

    // ---- A tile fill: thread = (freq i, stripe r0); rows r0+4*it, it<36 ----
    // value arithmetic identical to r18; addresses = 2 const bases + imm offsets
    {
        const float* const rd = &sBase[r0];
        const unsigned base0 = (unsigned)((i * 4) ^ (r0 << 4)) + (unsigned)r0 * 256;
        char* const wr0 = (char*)sA + base0;          // even it (row&7 == r0)
        char* const wr1 = (char*)sA + (base0 ^ 64u);  // odd it  (row&7 == r0+4)
#pragma unroll
        for (int it = 0; it < 36; ++it) {
            const float base = rd[it * 4];                    // sBase[r0 + 4*it]
            const float rev0 = base * dv2;                    // radians->revs folded
            const float rev  = rev0 - floorf(rev0);           // v_fract: [0,1) revs
            const float s = __builtin_amdgcn_sinf(rev);
            const float c = __builtin_amdgcn_cosf(rev);
            const unsigned int pack = __builtin_amdgcn_perm(
                __float_as_uint(c), __float_as_uint(s), 0x07060302u);
            char* const wp = (it & 1) ? wr1 : wr0;
            *(unsigned int*)(wp + it * 1024) = pack;          // row*256 = r0*256 + it*1024
        }
    }
    __syncthreads();

    // ---- MFMA GEMM: wave w owns g-tiles {2w, 2w+1}; A-frag read ONCE -------
    const int wid  = t >> 6;        // 0..3
    const int lane = t & 63;
    const int rlo  = lane & 15;     // A row within tile / B col (g)
    const int kseg = lane >> 4;     // k sub-segment

    const short8_t* wf = (const short8_t*)g_wfrag;
    short8_t wdb[2][4], wab[2][4];
#pragma unroll
    for (int gt = 0; gt < 2; ++gt) {
        const int gtile = wid * 2 + gt;
#pragma unroll
        for (int kt = 0; kt < 4; ++kt) {
            wdb[gt][kt] = wf[(gtile * 4 + kt) * 64 + lane];
            wab[gt][kt] = wf[((8 + gtile) * 4 + kt) * 64 + lane];
        }
    }

    const char* sAb = (const char*)sA;
    f32x4_t accd[2] = {{0.f,0.f,0.f,0.f}, {0.f,0.f,0.f,0.f}};
#pragma unroll
    for (int kt = 0; kt < 4; ++kt) {
        int byte = rlo * 256 + kt * 64 + kseg * 16;
        byte ^= (rlo & 7) << 4;
        const short8_t af = *(const short8_t*)(sAb + byte);
        accd[0] = __builtin_amdgcn_mfma_f32_16x16x32_bf16(af, wdb[0][kt], accd[0], 0, 0, 0);
        accd[1] = __builtin_amdgcn_mfma_f32_16x16x32_bf16(af, wdb[1][kt], accd[1], 0, 0, 0);
    }

    f32x4_t amax[2] = {{0.f,0.f,0.f,0.f}, {0.f,0.f,0.f,0.f}};
#pragma unroll
    for (int k = 0; k < KNN; ++k) {
        f32x4_t acc0 = {0.f,0.f,0.f,0.f};
        f32x4_t acc1 = {0.f,0.f,0.f,0.f};
        const int rowb = MT + k * 16 + rlo;
#pragma unroll
        for (int kt = 0; kt < 4; ++kt) {
            int byte = rowb * 256 + kt * 64 + kseg * 16;
            byte ^= (rowb & 7) << 4;
            const short8_t af = *(const short8_t*)(sAb + byte);
            acc0 = __builtin_amdgcn_mfma_f32_16x16x32_bf16(af, wab[0][kt], acc0, 0, 0, 0);
            acc1 = __builtin_amdgcn_mfma_f32_16x16x32_bf16(af, wab[1][kt], acc1, 0, 0, 0);
        }
        if (k == 0) { amax[0] = acc0; amax[1] = acc1; }
        else {
#pragma unroll
            for (int r = 0; r < 4; ++r) {
                amax[0][r] = fmaxf(amax[0][r], acc0[r]);
                amax[1][r] = fmaxf(amax[1][r], acc1[r]);
            }
        }
    }

    // ---- epilogue: C/D mapping col=lane&15 (g), row=(lane>>4)*4+reg (m) ----
#pragma unroll
    for (int gt = 0; gt < 2; ++gt) {
        const int g = (wid * 2 + gt) * 16 + rlo;
        const float bdv = bd[g];
        const float bav = ba[g];
#pragma unroll
        for (int r = 0; r < 4; ++r) {
            const int m = m0 + kseg * 4 + r;
            out[(n * N_PTS + m) * HID + g] = accd[gt][r] + bdv + amax[gt][r] + bav;
        }
    }
}

extern "C" void kernel_launch(void* const* d_in, const int* in_sizes, int n_in,
                              void* d_out, int out_size, void* d_ws, size_t ws_size,
                              hipStream_t stream) {
    (void)in_sizes; (void)n_in; (void)out_size; (void)d_ws; (void)ws_size;
    const float* points = (const float*)d_in[0];
    const float* Wd     = (const float*)d_in[1];
    const float* bd     = (const float*)d_in[2];
    const float* Wa     = (const float*)d_in[3];
    const float* ba     = (const float*)d_in[4];
    float* out = (float*)d_out;

    prep_kernel<<<N_PTS, 64, 0, stream>>>(points, Wd, Wa);

    dim3 grid(N_PTS / MT, N_PTS);
    main_kernel<<<grid, NTHREADS, 0, stream>>>(points, bd, ba, out);
}